// Round 3
// baseline (278.551 us; speedup 1.0000x reference)
//
#include <hip/hip_runtime.h>

// HungarianCELoss — analytic collapse of the 120-perm matching.
// targets has only 2 distinct rows (fg, bg=1-fg) => argmin over perms ==
// argmin_k (cost_fg[k]-cost_bg[k]), ties -> smallest k (lex order of perms).
// Per-element identities (x = slot logit, fg = target):
//   d  = softplus(x) - x = log1p(exp(-|x|)) + max(-x,0);  sigmoid(x) = exp(-d)
//   sum_k A_k = sum d (all k,n) + sum_k XF_k,  C_k = 2*XF_k - X_k
//   answer = [sum_k A_k - C_{k*}] summed over b, / (B*K*N)
//
// R7: single fused kernel. pass1 body identical to R6 (block = (b,segment)
// across all K planes, target read once into registers, nontemporal loads).
// pass2 is folded in via the last-block-done pattern: each block stores its
// 26 partials to ws, release-fences, bumps a device-scope counter; the
// 1280th block acquire-fences and does the tiny final reduction. Counter
// self-resets for graph replay. No block waits on another -> no
// dispatch-order assumption, no deadlock.

#define BB 64
#define KK 5
#define NPIX 102400              // 320*320
#define Q 20                     // segments per (b) plane
#define SEG (NPIX / Q)           // 5120 floats = 20 KB
#define THREADS 256
#define ITERS (SEG / (THREADS * 4))   // 5 float4-iterations per thread
#define REC 32                   // floats per (b,q) record; 26 used
#define NVAL 26                  // 5 stats x 5 k + Tf
#define NBLK (BB * Q)            // 1280 blocks

typedef float f4 __attribute__((ext_vector_type(4)));

__device__ unsigned int g_done = 0;   // persists across launches; self-reset

__global__ void hung_fused(const float* __restrict__ slot,   // (B,K,N)
                           const float* __restrict__ tgt,    // (B,1,N)
                           float* __restrict__ ws,           // (NBLK, REC)
                           float* __restrict__ out)
{
    const int bid = blockIdx.x;          // b*Q + q
    const int b   = bid / Q;
    const int q   = bid - b * Q;

    const float* sb = slot + (size_t)b * KK * NPIX + q * SEG;
    const float* t  = tgt  + (size_t)b * NPIX      + q * SEG;

    float aX[KK]  = {0,0,0,0,0};
    float aXF[KK] = {0,0,0,0,0};
    float aS[KK]  = {0,0,0,0,0};
    float aSF[KK] = {0,0,0,0,0};
    float aPX[KK] = {0,0,0,0,0};
    float Tf = 0.f;

    const int base = threadIdx.x * 4;
    #pragma unroll
    for (int i = 0; i < ITERS; ++i) {
        const int off = base + i * (THREADS * 4);
        const f4 fg4 = __builtin_nontemporal_load(
            reinterpret_cast<const f4*>(t + off));
        f4 x4[KK];
        #pragma unroll
        for (int k = 0; k < KK; ++k)
            x4[k] = __builtin_nontemporal_load(
                reinterpret_cast<const f4*>(sb + (size_t)k * NPIX + off));

        Tf += (fg4.x + fg4.y) + (fg4.z + fg4.w);

        #pragma unroll
        for (int k = 0; k < KK; ++k) {
            #pragma unroll
            for (int j = 0; j < 4; ++j) {
                const float x  = x4[k][j];
                const float fg = fg4[j];
                const float e  = __expf(-fabsf(x));     // exp(-|x|)
                const float L  = __logf(1.0f + e);      // log1p(exp(-|x|))
                const float d  = L + fmaxf(-x, 0.0f);   // softplus(x) - x
                const float s  = __expf(-d);            // sigmoid(x)
                aPX[k] += d;
                aX[k]  += x;
                aXF[k]  = fmaf(x, fg, aXF[k]);
                aS[k]  += s;
                aSF[k]  = fmaf(s, fg, aSF[k]);
            }
        }
    }

    // pack 26 block-partial values, reduce per-wave butterfly + LDS combine
    float v[NVAL];
    #pragma unroll
    for (int k = 0; k < KK; ++k) {
        v[k*5+0] = aX[k];  v[k*5+1] = aXF[k]; v[k*5+2] = aS[k];
        v[k*5+3] = aSF[k]; v[k*5+4] = aPX[k];
    }
    v[25] = Tf;

    #pragma unroll
    for (int jv = 0; jv < NVAL; ++jv) {
        float x = v[jv];
        #pragma unroll
        for (int off = 32; off > 0; off >>= 1) x += __shfl_down(x, off, 64);
        v[jv] = x;
    }
    __shared__ float red[THREADS / 64][NVAL];
    const int lane = threadIdx.x & 63;
    const int w    = threadIdx.x >> 6;
    if (lane == 0) {
        #pragma unroll
        for (int jv = 0; jv < NVAL; ++jv) red[w][jv] = v[jv];
    }
    __syncthreads();
    if (threadIdx.x < NVAL) {
        const int jv = threadIdx.x;
        ws[(size_t)bid * REC + jv] =
            red[0][jv] + red[1][jv] + red[2][jv] + red[3][jv];
        __threadfence();               // release: ws record device-visible
    }
    __syncthreads();

    // ---- last-block-done: the 1280th block to finish does the final pass ----
    __shared__ int is_last;
    if (threadIdx.x == 0) {
        const unsigned int c = atomicAdd(&g_done, 1u);
        is_last = (c == NBLK - 1);
        if (is_last) atomicExch(&g_done, 0u);   // reset for next graph replay
    }
    __syncthreads();
    if (!is_last) return;
    __threadfence();                   // acquire: see all blocks' ws records

    __shared__ float red2[BB][KK][6];  // X, XF, S, SF, PX, (Tf at k==0)
    for (int p = threadIdx.x; p < BB * KK; p += THREADS) {
        const int pb = p / KK, pk = p - pb * KK;
        float acc[5] = {0, 0, 0, 0, 0};
        float tf = 0.f;
        for (int qq = 0; qq < Q; ++qq) {
            const float* r = ws + (size_t)(pb * Q + qq) * REC;
            #pragma unroll
            for (int c = 0; c < 5; ++c) acc[c] += r[pk * 5 + c];
            if (pk == 0) tf += r[25];
        }
        #pragma unroll
        for (int c = 0; c < 5; ++c) red2[pb][pk][c] = acc[c];
        if (pk == 0) red2[pb][0][5] = tf;
    }
    __syncthreads();
    if (threadIdx.x < BB) {            // lanes 0..63 of wave 0: one image each
        const int ib = threadIdx.x;
        const float Tfv = red2[ib][0][5];
        const float Tb  = (float)NPIX - Tfv;
        float best = 3.402823466e+38f; int kb = 0;
        float xfsum = 0.f, px = 0.f;
        #pragma unroll
        for (int k = 0; k < KK; ++k) {
            const float Sv = red2[ib][k][2], Iv = red2[ib][k][3]; // S_k, inter_fg
            const float cf = 1.f - Iv / (Sv + Tfv - Iv + 1e-6f);
            const float Ib = Sv - Iv;
            const float cb = 1.f - Ib / (Sv + Tb - Ib + 1e-6f);
            const float dd = cf - cb;
            if (dd < best) { best = dd; kb = k; }  // strict < : ties -> smallest k
            xfsum += red2[ib][k][1];
            px    += red2[ib][k][4];
        }
        float res = px + xfsum - (2.f * red2[ib][kb][1] - red2[ib][kb][0]); // - C_{k*}
        #pragma unroll
        for (int off = 32; off > 0; off >>= 1) res += __shfl_down(res, off, 64);
        if (ib == 0) out[0] = res * (1.0f / 32768000.0f);   // / (B*K*N)
    }
}

extern "C" void kernel_launch(void* const* d_in, const int* in_sizes, int n_in,
                              void* d_out, int out_size, void* d_ws, size_t ws_size,
                              hipStream_t stream) {
    // setup_inputs order: fg_logits (unused by reference!), slot_logits, target
    const float* slot = (const float*)d_in[1];
    const float* tgt  = (const float*)d_in[2];
    float* out = (float*)d_out;
    float* ws  = (float*)d_ws;

    hung_fused<<<NBLK, THREADS, 0, stream>>>(slot, tgt, ws, out);
}

// Round 4
// 270.264 us; speedup vs baseline: 1.0307x; 1.0307x over previous
//
#include <hip/hip_runtime.h>

// HungarianCELoss — analytic collapse of the 120-perm matching.
// targets has only 2 distinct rows (fg, bg=1-fg) => argmin over perms ==
// argmin_k (cost_fg[k]-cost_bg[k]), ties -> smallest k (lex order of perms).
// Per-element identities (x = slot logit, fg = target):
//   d  = softplus(x) - x = log1p(exp(-|x|)) + max(-x,0);  sigmoid(x) = exp(-d)
//   sum_k A_k = sum d (all k,n) + sum_k XF_k,  C_k = 2*XF_k - X_k
//   answer = [sum_k A_k - C_{k*}] summed over b, / (B*K*N)
//
// R8: revert R7's fusion (per-block __threadfence = L2 writeback x1280 and
// the single-block tail cost ~57 µs — measured). Back to R6's two-kernel
// shape with two LATENCY fixes (R7 counters: 747 GB/s, VALUBusy 21% ->
// latency-bound, not BW-bound):
//  - no nontemporal: inputs are re-read every graph replay; nt blocked
//    L2/L3 allocation and forced ~900-cyc HBM refetches. Let caches work.
//  - depth-2 software prefetch (issue iter i+1's 6 loads before computing
//    iter i) + __launch_bounds__(256,5): VGPR budget ~102 (need ~84), so
//    ~12 loads in flight per wave instead of ~6, without dropping below
//    the 20 waves/CU this grid supplies.

#define BB 64
#define KK 5
#define NPIX 102400              // 320*320
#define Q 20                     // segments per (b) plane
#define SEG (NPIX / Q)           // 5120 floats = 20 KB
#define THREADS 256
#define ITERS (SEG / (THREADS * 4))   // 5 float4-iterations per thread
#define REC 32                   // floats per (b,q) record; 26 used
#define NVAL 26                  // 5 stats x 5 k + Tf
#define NBLK (BB * Q)            // 1280 blocks

typedef float f4 __attribute__((ext_vector_type(4)));

__global__ __launch_bounds__(THREADS, 5)
void hung_pass1(const float* __restrict__ slot,   // (B,K,N)
                const float* __restrict__ tgt,    // (B,1,N)
                float* __restrict__ ws)           // (NBLK, REC)
{
    const int bid = blockIdx.x;          // b*Q + q
    const int b   = bid / Q;
    const int q   = bid - b * Q;

    const float* sb = slot + (size_t)b * KK * NPIX + q * SEG;
    const float* t  = tgt  + (size_t)b * NPIX      + q * SEG;

    float aX[KK]  = {0,0,0,0,0};
    float aXF[KK] = {0,0,0,0,0};
    float aS[KK]  = {0,0,0,0,0};
    float aSF[KK] = {0,0,0,0,0};
    float aPX[KK] = {0,0,0,0,0};
    float Tf = 0.f;

    const int base = threadIdx.x * 4;

    // prefetch iteration 0
    f4 cf = *reinterpret_cast<const f4*>(t + base);
    f4 cx[KK];
    #pragma unroll
    for (int k = 0; k < KK; ++k)
        cx[k] = *reinterpret_cast<const f4*>(sb + (size_t)k * NPIX + base);

    #pragma unroll
    for (int i = 0; i < ITERS; ++i) {
        f4 nf;
        f4 nx[KK];
        if (i + 1 < ITERS) {             // issue next-iter loads FIRST
            const int noff = base + (i + 1) * (THREADS * 4);
            nf = *reinterpret_cast<const f4*>(t + noff);
            #pragma unroll
            for (int k = 0; k < KK; ++k)
                nx[k] = *reinterpret_cast<const f4*>(sb + (size_t)k * NPIX + noff);
        }

        Tf += (cf.x + cf.y) + (cf.z + cf.w);
        #pragma unroll
        for (int k = 0; k < KK; ++k) {
            #pragma unroll
            for (int j = 0; j < 4; ++j) {
                const float x  = cx[k][j];
                const float fg = cf[j];
                const float e  = __expf(-fabsf(x));     // exp(-|x|)
                const float L  = __logf(1.0f + e);      // log1p(exp(-|x|))
                const float d  = L + fmaxf(-x, 0.0f);   // softplus(x) - x
                const float s  = __expf(-d);            // sigmoid(x)
                aPX[k] += d;
                aX[k]  += x;
                aXF[k]  = fmaf(x, fg, aXF[k]);
                aS[k]  += s;
                aSF[k]  = fmaf(s, fg, aSF[k]);
            }
        }

        if (i + 1 < ITERS) {
            cf = nf;
            #pragma unroll
            for (int k = 0; k < KK; ++k) cx[k] = nx[k];
        }
    }

    // pack 26 block-partial values, reduce per-wave butterfly + LDS combine
    float v[NVAL];
    #pragma unroll
    for (int k = 0; k < KK; ++k) {
        v[k*5+0] = aX[k];  v[k*5+1] = aXF[k]; v[k*5+2] = aS[k];
        v[k*5+3] = aSF[k]; v[k*5+4] = aPX[k];
    }
    v[25] = Tf;

    #pragma unroll
    for (int jv = 0; jv < NVAL; ++jv) {
        float x = v[jv];
        #pragma unroll
        for (int off = 32; off > 0; off >>= 1) x += __shfl_down(x, off, 64);
        v[jv] = x;
    }
    __shared__ float red[THREADS / 64][NVAL];
    const int lane = threadIdx.x & 63;
    const int w    = threadIdx.x >> 6;
    if (lane == 0) {
        #pragma unroll
        for (int jv = 0; jv < NVAL; ++jv) red[w][jv] = v[jv];
    }
    __syncthreads();
    if (threadIdx.x < NVAL) {
        const int jv = threadIdx.x;
        ws[(size_t)bid * REC + jv] =
            red[0][jv] + red[1][jv] + red[2][jv] + red[3][jv];
    }
}

__global__ __launch_bounds__(320) void hung_pass2(const float* __restrict__ ws,
                                                  float* __restrict__ out)
{
    __shared__ float red[BB][KK][6];     // X, XF, S, SF, PX, (Tf at k==0)
    const int t = threadIdx.x;           // t == b*KK + k  (320 threads exactly)
    {
        const int b = t / KK, k = t - (t / KK) * KK;
        float v[5] = {0, 0, 0, 0, 0};
        float tf = 0.f;
        for (int q = 0; q < Q; ++q) {
            const float* p = ws + (size_t)(b * Q + q) * REC;
            #pragma unroll
            for (int c = 0; c < 5; ++c) v[c] += p[k * 5 + c];
            if (k == 0) tf += p[25];
        }
        #pragma unroll
        for (int c = 0; c < 5; ++c) red[b][k][c] = v[c];
        if (k == 0) red[b][0][5] = tf;
    }
    __syncthreads();
    if (t < BB) {                        // wave 0: one image per lane
        const int b = t;
        const float Tf = red[b][0][5];
        const float Tb = (float)NPIX - Tf;
        float best = 3.402823466e+38f; int kb = 0;
        float xfsum = 0.f, px = 0.f;
        #pragma unroll
        for (int k = 0; k < KK; ++k) {
            const float Sv = red[b][k][2], Iv = red[b][k][3];  // S_k, inter_fg
            const float cf = 1.f - Iv / (Sv + Tf - Iv + 1e-6f);
            const float Ib = Sv - Iv;
            const float cb = 1.f - Ib / (Sv + Tb - Ib + 1e-6f);
            const float dd = cf - cb;
            if (dd < best) { best = dd; kb = k; }  // strict < : ties -> smallest k
            xfsum += red[b][k][1];
            px    += red[b][k][4];
        }
        float res = px + xfsum - (2.f * red[b][kb][1] - red[b][kb][0]);  // - C_{k*}
        #pragma unroll
        for (int off = 32; off > 0; off >>= 1) res += __shfl_down(res, off, 64);
        if (b == 0) out[0] = res * (1.0f / 32768000.0f);   // / (B*K*N)
    }
}

extern "C" void kernel_launch(void* const* d_in, const int* in_sizes, int n_in,
                              void* d_out, int out_size, void* d_ws, size_t ws_size,
                              hipStream_t stream) {
    // setup_inputs order: fg_logits (unused by reference!), slot_logits, target
    const float* slot = (const float*)d_in[1];
    const float* tgt  = (const float*)d_in[2];
    float* out = (float*)d_out;
    float* ws  = (float*)d_ws;

    hung_pass1<<<NBLK, THREADS, 0, stream>>>(slot, tgt, ws);
    hung_pass2<<<1, 320, 0, stream>>>(ws, out);
}

// Round 5
// 239.633 us; speedup vs baseline: 1.1624x; 1.1278x over previous
//
#include <hip/hip_runtime.h>

// HungarianCELoss — analytic collapse of the 120-perm matching.
// targets has only 2 distinct rows (fg, bg=1-fg) => argmin over perms ==
// argmin_k (cost_fg[k]-cost_bg[k]), ties -> smallest k (lex order of perms).
// Per-element identities (x = slot logit, fg = target):
//   d  = softplus(x) - x = log1p(exp(-|x|)) + max(-x,0);  sigmoid(x) = exp(-d)
//   sum_k A_k = sum d (all k,n) + sum_k XF_k,  C_k = 2*XF_k - X_k
//   answer = [sum_k A_k - C_{k*}] summed over b, / (B*K*N)
//
// R9: R8's manual prefetch + __launch_bounds__ spilled to scratch
// (VGPR 48, 96 MB spill writes — measured). Remove both. Get MLP the
// cheap way instead: ITERS=2 (Q=50, SEG=2048 floats, 3200 blocks).
// Full unroll lets the compiler hoist all 12 independent dwordx4 loads
// (48 dest VGPRs, ~90 total — no spill, 5 waves/SIMD) ahead of compute,
// and 12.5 blocks/CU backfills the tail instead of R6's one co-resident
// wavefront of 1280. Plain cached loads (nt hurt: inputs re-read every
// graph replay; fills evict L3 but partial survival is still worth ~30 MB).

#define BB 64
#define KK 5
#define NPIX 102400              // 320*320
#define Q 50                     // segments per (b) plane
#define SEG (NPIX / Q)           // 2048 floats = 8 KB
#define THREADS 256
#define ITERS (SEG / (THREADS * 4))   // 2 float4-iterations per thread
#define REC 32                   // floats per (b,q) record; 26 used
#define NVAL 26                  // 5 stats x 5 k + Tf
#define NBLK (BB * Q)            // 3200 blocks

typedef float f4 __attribute__((ext_vector_type(4)));

__global__ void hung_pass1(const float* __restrict__ slot,   // (B,K,N)
                           const float* __restrict__ tgt,    // (B,1,N)
                           float* __restrict__ ws)           // (NBLK, REC)
{
    const int bid = blockIdx.x;          // b*Q + q
    const int b   = bid / Q;
    const int q   = bid - b * Q;

    const float* sb = slot + (size_t)b * KK * NPIX + q * SEG;
    const float* t  = tgt  + (size_t)b * NPIX      + q * SEG;

    float aX[KK]  = {0,0,0,0,0};
    float aXF[KK] = {0,0,0,0,0};
    float aS[KK]  = {0,0,0,0,0};
    float aSF[KK] = {0,0,0,0,0};
    float aPX[KK] = {0,0,0,0,0};
    float Tf = 0.f;

    const int base = threadIdx.x * 4;
    #pragma unroll
    for (int i = 0; i < ITERS; ++i) {
        const int off = base + i * (THREADS * 4);
        const f4 fg4 = *reinterpret_cast<const f4*>(t + off);
        f4 x4[KK];
        #pragma unroll
        for (int k = 0; k < KK; ++k)
            x4[k] = *reinterpret_cast<const f4*>(sb + (size_t)k * NPIX + off);

        Tf += (fg4.x + fg4.y) + (fg4.z + fg4.w);

        #pragma unroll
        for (int k = 0; k < KK; ++k) {
            #pragma unroll
            for (int j = 0; j < 4; ++j) {
                const float x  = x4[k][j];
                const float fg = fg4[j];
                const float e  = __expf(-fabsf(x));     // exp(-|x|)
                const float L  = __logf(1.0f + e);      // log1p(exp(-|x|))
                const float d  = L + fmaxf(-x, 0.0f);   // softplus(x) - x
                const float s  = __expf(-d);            // sigmoid(x)
                aPX[k] += d;
                aX[k]  += x;
                aXF[k]  = fmaf(x, fg, aXF[k]);
                aS[k]  += s;
                aSF[k]  = fmaf(s, fg, aSF[k]);
            }
        }
    }

    // pack 26 block-partial values, reduce per-wave butterfly + LDS combine
    float v[NVAL];
    #pragma unroll
    for (int k = 0; k < KK; ++k) {
        v[k*5+0] = aX[k];  v[k*5+1] = aXF[k]; v[k*5+2] = aS[k];
        v[k*5+3] = aSF[k]; v[k*5+4] = aPX[k];
    }
    v[25] = Tf;

    #pragma unroll
    for (int jv = 0; jv < NVAL; ++jv) {
        float x = v[jv];
        #pragma unroll
        for (int off = 32; off > 0; off >>= 1) x += __shfl_down(x, off, 64);
        v[jv] = x;
    }
    __shared__ float red[THREADS / 64][NVAL];
    const int lane = threadIdx.x & 63;
    const int w    = threadIdx.x >> 6;
    if (lane == 0) {
        #pragma unroll
        for (int jv = 0; jv < NVAL; ++jv) red[w][jv] = v[jv];
    }
    __syncthreads();
    if (threadIdx.x < NVAL) {
        const int jv = threadIdx.x;
        ws[(size_t)bid * REC + jv] =
            red[0][jv] + red[1][jv] + red[2][jv] + red[3][jv];
    }
}

__global__ __launch_bounds__(320) void hung_pass2(const float* __restrict__ ws,
                                                  float* __restrict__ out)
{
    __shared__ float red[BB][KK][6];     // X, XF, S, SF, PX, (Tf at k==0)
    const int t = threadIdx.x;           // t == b*KK + k  (320 threads exactly)
    {
        const int b = t / KK, k = t - (t / KK) * KK;
        float v[5] = {0, 0, 0, 0, 0};
        float tf = 0.f;
        for (int q = 0; q < Q; ++q) {
            const float* p = ws + (size_t)(b * Q + q) * REC;
            #pragma unroll
            for (int c = 0; c < 5; ++c) v[c] += p[k * 5 + c];
            if (k == 0) tf += p[25];
        }
        #pragma unroll
        for (int c = 0; c < 5; ++c) red[b][k][c] = v[c];
        if (k == 0) red[b][0][5] = tf;
    }
    __syncthreads();
    if (t < BB) {                        // wave 0: one image per lane
        const int b = t;
        const float Tf = red[b][0][5];
        const float Tb = (float)NPIX - Tf;
        float best = 3.402823466e+38f; int kb = 0;
        float xfsum = 0.f, px = 0.f;
        #pragma unroll
        for (int k = 0; k < KK; ++k) {
            const float Sv = red[b][k][2], Iv = red[b][k][3];  // S_k, inter_fg
            const float cf = 1.f - Iv / (Sv + Tf - Iv + 1e-6f);
            const float Ib = Sv - Iv;
            const float cb = 1.f - Ib / (Sv + Tb - Ib + 1e-6f);
            const float dd = cf - cb;
            if (dd < best) { best = dd; kb = k; }  // strict < : ties -> smallest k
            xfsum += red[b][k][1];
            px    += red[b][k][4];
        }
        float res = px + xfsum - (2.f * red[b][kb][1] - red[b][kb][0]);  // - C_{k*}
        #pragma unroll
        for (int off = 32; off > 0; off >>= 1) res += __shfl_down(res, off, 64);
        if (b == 0) out[0] = res * (1.0f / 32768000.0f);   // / (B*K*N)
    }
}

extern "C" void kernel_launch(void* const* d_in, const int* in_sizes, int n_in,
                              void* d_out, int out_size, void* d_ws, size_t ws_size,
                              hipStream_t stream) {
    // setup_inputs order: fg_logits (unused by reference!), slot_logits, target
    const float* slot = (const float*)d_in[1];
    const float* tgt  = (const float*)d_in[2];
    float* out = (float*)d_out;
    float* ws  = (float*)d_ws;

    hung_pass1<<<NBLK, THREADS, 0, stream>>>(slot, tgt, ws);
    hung_pass2<<<1, 320, 0, stream>>>(ws, out);
}

// Round 6
// 235.998 us; speedup vs baseline: 1.1803x; 1.0154x over previous
//
#include <hip/hip_runtime.h>

// HungarianCELoss — analytic collapse of the 120-perm matching.
// targets has only 2 distinct rows (fg, bg=1-fg) => argmin over perms ==
// argmin_k (cost_fg[k]-cost_bg[k]), ties -> smallest k (lex order of perms).
// Per-element identities (x = slot logit, fg = target):
//   d  = softplus(x) - x = log1p(exp(-|x|)) + max(-x,0);  sigmoid(x) = exp(-d)
//   sum_k A_k = sum d (all k,n) + sum_k XF_k,  C_k = 2*XF_k - X_k
//   answer = [sum_k A_k - C_{k*}] summed over b, / (B*K*N)
//
// R10: R9's VGPR_Count=48 proved the compiler SINKS each load to its use
// (26 accs + 24 load-dests don't fit in 48) -> 1-2 loads in flight, latency
// bound at ~2 TB/s. R8's prefetch was right but __launch_bounds__(256,5)
// forced the 48-reg budget -> 96 MB scratch spill. So: depth-2 prefetch,
// NO launch_bounds (default 256-reg budget), alternating A/B named buffers
// (no register copies, all indices compile-time), and sched_barrier(0)
// between prefetch-issue and compute to forbid sinking. ~95 VGPR -> 4
// waves/SIMD, 6 KB in flight per wave during compute.

#define BB 64
#define KK 5
#define NPIX 102400              // 320*320
#define Q 20                     // segments per (b) plane
#define SEG (NPIX / Q)           // 5120 floats = 20 KB
#define THREADS 256
#define ITERS (SEG / (THREADS * 4))   // 5 float4-iterations per thread
#define REC 32                   // floats per (b,q) record; 26 used
#define NVAL 26                  // 5 stats x 5 k + Tf
#define NBLK (BB * Q)            // 1280 blocks

typedef float f4 __attribute__((ext_vector_type(4)));

#define LOADSEG(FGV, XV, OFF)                                              \
    do {                                                                   \
        const int _o = (OFF);                                              \
        FGV = *reinterpret_cast<const f4*>(t + _o);                        \
        _Pragma("unroll")                                                  \
        for (int k = 0; k < KK; ++k)                                       \
            XV[k] = *reinterpret_cast<const f4*>(sb + (size_t)k * NPIX + _o); \
    } while (0)

#define CONSUME(FGV, XV)                                                   \
    do {                                                                   \
        Tf += (FGV.x + FGV.y) + (FGV.z + FGV.w);                           \
        _Pragma("unroll")                                                  \
        for (int k = 0; k < KK; ++k) {                                     \
            _Pragma("unroll")                                              \
            for (int j = 0; j < 4; ++j) {                                  \
                const float x  = XV[k][j];                                 \
                const float fg = FGV[j];                                   \
                const float e  = __expf(-fabsf(x));                        \
                const float L  = __logf(1.0f + e);                         \
                const float d  = L + fmaxf(-x, 0.0f);                      \
                const float s  = __expf(-d);                               \
                aPX[k] += d;                                               \
                aX[k]  += x;                                               \
                aXF[k]  = fmaf(x, fg, aXF[k]);                             \
                aS[k]  += s;                                               \
                aSF[k]  = fmaf(s, fg, aSF[k]);                             \
            }                                                              \
        }                                                                  \
    } while (0)

__global__ void hung_pass1(const float* __restrict__ slot,   // (B,K,N)
                           const float* __restrict__ tgt,    // (B,1,N)
                           float* __restrict__ ws)           // (NBLK, REC)
{
    const int bid = blockIdx.x;          // b*Q + q
    const int b   = bid / Q;
    const int q   = bid - b * Q;

    const float* sb = slot + (size_t)b * KK * NPIX + q * SEG;
    const float* t  = tgt  + (size_t)b * NPIX      + q * SEG;

    float aX[KK]  = {0,0,0,0,0};
    float aXF[KK] = {0,0,0,0,0};
    float aS[KK]  = {0,0,0,0,0};
    float aSF[KK] = {0,0,0,0,0};
    float aPX[KK] = {0,0,0,0,0};
    float Tf = 0.f;

    const int base = threadIdx.x * 4;

    f4 Af, Bf;
    f4 Ax[KK], Bx[KK];

    LOADSEG(Af, Ax, base);               // prefetch iteration 0 into A

    #pragma unroll
    for (int i = 0; i < ITERS; ++i) {
        const bool useA = ((i & 1) == 0);    // compile-time after unroll
        if (i + 1 < ITERS) {                 // issue next-iter loads FIRST
            const int noff = base + (i + 1) * (THREADS * 4);
            if (useA) LOADSEG(Bf, Bx, noff);
            else      LOADSEG(Af, Ax, noff);
        }
        // forbid the scheduler from sinking the prefetch loads below the
        // compute (R9's VGPR=48 shows it does exactly that when allowed)
        __builtin_amdgcn_sched_barrier(0);
        if (useA) CONSUME(Af, Ax);
        else      CONSUME(Bf, Bx);
    }

    // pack 26 block-partial values, reduce per-wave butterfly + LDS combine
    float v[NVAL];
    #pragma unroll
    for (int k = 0; k < KK; ++k) {
        v[k*5+0] = aX[k];  v[k*5+1] = aXF[k]; v[k*5+2] = aS[k];
        v[k*5+3] = aSF[k]; v[k*5+4] = aPX[k];
    }
    v[25] = Tf;

    #pragma unroll
    for (int jv = 0; jv < NVAL; ++jv) {
        float x = v[jv];
        #pragma unroll
        for (int off = 32; off > 0; off >>= 1) x += __shfl_down(x, off, 64);
        v[jv] = x;
    }
    __shared__ float red[THREADS / 64][NVAL];
    const int lane = threadIdx.x & 63;
    const int w    = threadIdx.x >> 6;
    if (lane == 0) {
        #pragma unroll
        for (int jv = 0; jv < NVAL; ++jv) red[w][jv] = v[jv];
    }
    __syncthreads();
    if (threadIdx.x < NVAL) {
        const int jv = threadIdx.x;
        ws[(size_t)bid * REC + jv] =
            red[0][jv] + red[1][jv] + red[2][jv] + red[3][jv];
    }
}

__global__ __launch_bounds__(320) void hung_pass2(const float* __restrict__ ws,
                                                  float* __restrict__ out)
{
    __shared__ float red[BB][KK][6];     // X, XF, S, SF, PX, (Tf at k==0)
    const int t = threadIdx.x;           // t == b*KK + k  (320 threads exactly)
    {
        const int b = t / KK, k = t - (t / KK) * KK;
        float v[5] = {0, 0, 0, 0, 0};
        float tf = 0.f;
        for (int q = 0; q < Q; ++q) {
            const float* p = ws + (size_t)(b * Q + q) * REC;
            #pragma unroll
            for (int c = 0; c < 5; ++c) v[c] += p[k * 5 + c];
            if (k == 0) tf += p[25];
        }
        #pragma unroll
        for (int c = 0; c < 5; ++c) red[b][k][c] = v[c];
        if (k == 0) red[b][0][5] = tf;
    }
    __syncthreads();
    if (t < BB) {                        // wave 0: one image per lane
        const int b = t;
        const float Tf = red[b][0][5];
        const float Tb = (float)NPIX - Tf;
        float best = 3.402823466e+38f; int kb = 0;
        float xfsum = 0.f, px = 0.f;
        #pragma unroll
        for (int k = 0; k < KK; ++k) {
            const float Sv = red[b][k][2], Iv = red[b][k][3];  // S_k, inter_fg
            const float cf = 1.f - Iv / (Sv + Tf - Iv + 1e-6f);
            const float Ib = Sv - Iv;
            const float cb = 1.f - Ib / (Sv + Tb - Ib + 1e-6f);
            const float dd = cf - cb;
            if (dd < best) { best = dd; kb = k; }  // strict < : ties -> smallest k
            xfsum += red[b][k][1];
            px    += red[b][k][4];
        }
        float res = px + xfsum - (2.f * red[b][kb][1] - red[b][kb][0]);  // - C_{k*}
        #pragma unroll
        for (int off = 32; off > 0; off >>= 1) res += __shfl_down(res, off, 64);
        if (b == 0) out[0] = res * (1.0f / 32768000.0f);   // / (B*K*N)
    }
}

extern "C" void kernel_launch(void* const* d_in, const int* in_sizes, int n_in,
                              void* d_out, int out_size, void* d_ws, size_t ws_size,
                              hipStream_t stream) {
    // setup_inputs order: fg_logits (unused by reference!), slot_logits, target
    const float* slot = (const float*)d_in[1];
    const float* tgt  = (const float*)d_in[2];
    float* out = (float*)d_out;
    float* ws  = (float*)d_ws;

    hung_pass1<<<NBLK, THREADS, 0, stream>>>(slot, tgt, ws);
    hung_pass2<<<1, 320, 0, stream>>>(ws, out);
}